// Round 14
// baseline (693.658 us; speedup 1.0000x reference)
//
#include <hip/hip_runtime.h>
#include <hip/hip_bf16.h>
#include <hip/hip_fp16.h>

#define NN   50000
#define NE   800000
#define NEP  850000   // NE + NN self loops
#define NG   64
#define HH   256      // 4 heads * 64 ch
#define DOUT 10
#define SCH  196      // scan chunk: 256*196 = 50176 >= NN

typedef __attribute__((ext_vector_type(8))) short bf16x8;
typedef __attribute__((ext_vector_type(4))) float f32x4;

__device__ inline float bf2f(ushort u) {
    union { unsigned int i; float f; } v; v.i = ((unsigned int)u) << 16; return v.f;
}
__device__ inline ushort f2bf(float f) {   // round-to-nearest-even (finite)
    union { float f; unsigned int i; } v; v.f = f;
    unsigned int x = v.i;
    return (ushort)((x + 0x7FFFu + ((x >> 16) & 1u)) >> 16);
}

// ---------------------------------------------------------------- h0 = x@A_W + A_b -> bf16 [NN,64]
__global__ __launch_bounds__(256) void k_lin0b(const float* __restrict__ x,
                                               const float* __restrict__ W,
                                               const float* __restrict__ b,
                                               ushort* __restrict__ out) {
    int idx = blockIdx.x * 256 + threadIdx.x;   // grid exactly NN*64
    int n = idx >> 6, c = idx & 63;
    if (n >= NN) return;
    float acc = b[c];
    #pragma unroll
    for (int k = 0; k < 16; ++k) acc = fmaf(x[n * 16 + k], W[k * 64 + c], acc);
    out[idx] = f2bf(acc);
}

// ---------------------------------------------------------------- degree histogram (deg passed zeroed)
__global__ __launch_bounds__(256) void k_degree(const int* __restrict__ ei, int* __restrict__ deg) {
    int e = blockIdx.x * 256 + threadIdx.x;
    if (e >= NEP) return;
    int dst = (e < NE) ? ei[NE + e] : (e - NE);
    atomicAdd(&deg[dst], 1);
}

// ---------------------------------------------------------------- 3-phase multi-block exclusive scan
__global__ __launch_bounds__(256) void k_scanA(const int* __restrict__ deg, int* __restrict__ bsum) {
    __shared__ int wsum[4];
    int b = blockIdx.x, t = threadIdx.x, lane = t & 63, w = t >> 6;
    int i = b * SCH + t;
    int v = (t < SCH && i < NN) ? deg[i] : 0;
    #pragma unroll
    for (int d = 1; d < 64; d <<= 1) v += __shfl_xor(v, d, 64);
    if (lane == 0) wsum[w] = v;
    __syncthreads();
    if (t == 0) bsum[b] = wsum[0] + wsum[1] + wsum[2] + wsum[3];
}
__global__ __launch_bounds__(256) void k_scanB(const int* __restrict__ bsum,
                                               int* __restrict__ boff,
                                               int* __restrict__ row_ptr) {
    __shared__ int wtot[4];
    int t = threadIdx.x, lane = t & 63, w = t >> 6;
    int v = bsum[t];
    int sc = v;
    #pragma unroll
    for (int d = 1; d < 64; d <<= 1) {
        int u = __shfl_up(sc, (unsigned)d, 64);
        if (lane >= d) sc += u;
    }
    if (lane == 63) wtot[w] = sc;
    __syncthreads();
    int woff = 0;
    #pragma unroll
    for (int k = 0; k < 4; ++k) woff += (k < w) ? wtot[k] : 0;
    boff[t] = woff + sc - v;                     // exclusive
    if (t == 0) row_ptr[NN] = NEP;
}
// C: row_ptr[i] = boff[b] + in-block exclusive; also zeroes deg (it becomes scatter cursor)
__global__ __launch_bounds__(256) void k_scanC(int* __restrict__ deg,
                                               const int* __restrict__ boff,
                                               int* __restrict__ row_ptr) {
    __shared__ int wtot[4];
    int b = blockIdx.x, t = threadIdx.x, lane = t & 63, w = t >> 6;
    int i = b * SCH + t;
    bool live = (t < SCH && i < NN);
    int v = live ? deg[i] : 0;
    int sc = v;
    #pragma unroll
    for (int d = 1; d < 64; d <<= 1) {
        int u = __shfl_up(sc, (unsigned)d, 64);
        if (lane >= d) sc += u;
    }
    if (lane == 63) wtot[w] = sc;
    __syncthreads();
    int woff = 0;
    #pragma unroll
    for (int k = 0; k < 4; ++k) woff += (k < w) ? wtot[k] : 0;
    if (live) { row_ptr[i] = boff[b] + woff + sc - v; deg[i] = 0; }
}

// ---------------------------------------------------------------- CSR scatter (cursor pre-zeroed by scanC)
__global__ __launch_bounds__(256) void k_scatter(const int* __restrict__ ei,
                                                 const int* __restrict__ row_ptr,
                                                 int* __restrict__ cursor,
                                                 int* __restrict__ col_idx) {
    int e = blockIdx.x * 256 + threadIdx.x;
    if (e >= NEP) return;
    int src, dst;
    if (e < NE) { src = ei[e]; dst = ei[NE + e]; }
    else        { src = e - NE; dst = e - NE; }
    int pos = atomicAdd(&cursor[dst], 1);
    col_idx[row_ptr[dst] + pos] = src;
}

// ---------------------------------------------------------------- W prep: fp32 [K,256] -> bf16 hi/lo col-major [256,K]
template <int K>
__global__ __launch_bounds__(256) void k_wprep(const float* __restrict__ W,
                                               ushort* __restrict__ Whi,
                                               ushort* __restrict__ Wlo) {
    int idx = blockIdx.x * 256 + threadIdx.x;   // grid exactly K*256/256
    int k = idx >> 8, col = idx & 255;
    float v = W[idx];
    ushort hi = f2bf(v);
    Whi[col * K + k] = hi;
    Wlo[col * K + k] = f2bf(v - bf2f(hi));      // residual: W ~ fp32-accurate as hi+lo
}

// ---------------------------------------------------------------- MFMA GEMM + fused score epilogue
template <int K>
__global__ __launch_bounds__(256) void k_gemm(const ushort* __restrict__ A,
                                              const ushort* __restrict__ Whi,
                                              const ushort* __restrict__ Wlo,
                                              ushort* __restrict__ C,
                                              const float* __restrict__ a_s,
                                              const float* __restrict__ a_d,
                                              float* __restrict__ ss,
                                              float* __restrict__ sd) {
    __shared__ ushort As[64][40];    // pad to 40 -> ~2-way banks
    __shared__ ushort Bh[256][40];
    __shared__ ushort Bl[256][40];
    int tid = threadIdx.x;
    int w = tid >> 6, l = tid & 63;
    int rl = l & 15, rg = l >> 4;
    int m0 = blockIdx.x * 64;
    f32x4 acc[4][4];
    #pragma unroll
    for (int i = 0; i < 4; ++i)
        #pragma unroll
        for (int j = 0; j < 4; ++j) acc[i][j] = (f32x4){0.f, 0.f, 0.f, 0.f};

    int arow = tid >> 2, ak8 = (tid & 3) << 3;
    for (int k0 = 0; k0 < K; k0 += 32) {
        {   // stage A 64x32
            int gr = m0 + arow; if (gr >= NN) gr = NN - 1;
            *reinterpret_cast<bf16x8*>(&As[arow][ak8]) =
                *reinterpret_cast<const bf16x8*>(&A[gr * K + k0 + ak8]);
        }
        #pragma unroll
        for (int j = 0; j < 4; ++j) {   // stage B 256x32 hi+lo (thread=col)
            *reinterpret_cast<bf16x8*>(&Bh[tid][j << 3]) =
                *reinterpret_cast<const bf16x8*>(&Whi[tid * K + k0 + (j << 3)]);
            *reinterpret_cast<bf16x8*>(&Bl[tid][j << 3]) =
                *reinterpret_cast<const bf16x8*>(&Wlo[tid * K + k0 + (j << 3)]);
        }
        __syncthreads();
        int kg = rg << 3;
        bf16x8 a_frag[4], bh_frag[4], bl_frag[4];
        #pragma unroll
        for (int rt = 0; rt < 4; ++rt)
            a_frag[rt] = *reinterpret_cast<const bf16x8*>(&As[rt * 16 + rl][kg]);
        #pragma unroll
        for (int ct = 0; ct < 4; ++ct) {
            int col = (w << 6) + ct * 16 + rl;
            bh_frag[ct] = *reinterpret_cast<const bf16x8*>(&Bh[col][kg]);
            bl_frag[ct] = *reinterpret_cast<const bf16x8*>(&Bl[col][kg]);
        }
        #pragma unroll
        for (int rt = 0; rt < 4; ++rt)
            #pragma unroll
            for (int ct = 0; ct < 4; ++ct) {
                acc[rt][ct] = __builtin_amdgcn_mfma_f32_16x16x32_bf16(
                    a_frag[rt], bh_frag[ct], acc[rt][ct], 0, 0, 0);
                acc[rt][ct] = __builtin_amdgcn_mfma_f32_16x16x32_bf16(
                    a_frag[rt], bl_frag[ct], acc[rt][ct], 0, 0, 0);
            }
        __syncthreads();
    }
    float as4[4], ad4[4];
    #pragma unroll
    for (int ct = 0; ct < 4; ++ct) {
        as4[ct] = a_s[(w << 6) + ct * 16 + rl];
        ad4[ct] = a_d[(w << 6) + ct * 16 + rl];
    }
    #pragma unroll
    for (int rt = 0; rt < 4; ++rt)
        #pragma unroll
        for (int reg = 0; reg < 4; ++reg) {
            int m = m0 + rt * 16 + (rg << 2) + reg;
            float ps = 0.f, pd = 0.f;
            #pragma unroll
            for (int ct = 0; ct < 4; ++ct) {
                float v = acc[rt][ct][reg];
                ps = fmaf(v, as4[ct], ps);
                pd = fmaf(v, ad4[ct], pd);
                if (m < NN) C[m * HH + (w << 6) + ct * 16 + rl] = f2bf(v);
            }
            #pragma unroll
            for (int d = 1; d < 16; d <<= 1) {
                ps += __shfl_xor(ps, d, 64);
                pd += __shfl_xor(pd, d, 64);
            }
            if (rl == 0 && m < NN) {
                ss[m * 4 + w] = ps;
                sd[m * 4 + w] = pd;
            }
        }
}

// ---------------------------------------------------------------- alpha precompute, 1 wave/node, lanes over edges
// alp[e][h] (fp16): softmax weight of edge e for head h (denominator folded in)
__global__ __launch_bounds__(256) void k_alpha(const float* __restrict__ ss,
                                               const float* __restrict__ sd,
                                               const int* __restrict__ row_ptr,
                                               const int* __restrict__ col_idx,
                                               ushort* __restrict__ alp) {
    int wid = threadIdx.x >> 6, lane = threadIdx.x & 63;
    int n = blockIdx.x * 4 + wid;                     // NN = 12500*4
    int rs = row_ptr[n], re = row_ptr[n + 1];
    float4 sdn = *reinterpret_cast<const float4*>(&sd[n * 4]);
    float m0 = -1e30f, m1 = -1e30f, m2 = -1e30f, m3 = -1e30f;
    float s0 = 0.f, s1 = 0.f, s2 = 0.f, s3 = 0.f;
    for (int e = rs + lane; e < re; e += 64) {
        int sn = col_idx[e];
        float4 t = *reinterpret_cast<const float4*>(&ss[sn * 4]);
        float c0 = t.x + sdn.x; c0 = (c0 > 0.f) ? c0 : 0.2f * c0;   // leaky_relu 0.2
        float c1 = t.y + sdn.y; c1 = (c1 > 0.f) ? c1 : 0.2f * c1;
        float c2 = t.z + sdn.z; c2 = (c2 > 0.f) ? c2 : 0.2f * c2;
        float c3 = t.w + sdn.w; c3 = (c3 > 0.f) ? c3 : 0.2f * c3;
        float mn, d;
        mn = fmaxf(m0, c0); d = __expf(fminf(m0, c0) - mn);
        s0 = (c0 > m0) ? fmaf(s0, d, 1.f) : (s0 + d); m0 = mn;
        mn = fmaxf(m1, c1); d = __expf(fminf(m1, c1) - mn);
        s1 = (c1 > m1) ? fmaf(s1, d, 1.f) : (s1 + d); m1 = mn;
        mn = fmaxf(m2, c2); d = __expf(fminf(m2, c2) - mn);
        s2 = (c2 > m2) ? fmaf(s2, d, 1.f) : (s2 + d); m2 = mn;
        mn = fmaxf(m3, c3); d = __expf(fminf(m3, c3) - mn);
        s3 = (c3 > m3) ? fmaf(s3, d, 1.f) : (s3 + d); m3 = mn;
    }
    // butterfly merge of (m,s) online-softmax states across the wave
    #pragma unroll
    for (int dd = 1; dd < 64; dd <<= 1) {
        float mo, so, mn, f;
        mo = __shfl_xor(m0, dd, 64); so = __shfl_xor(s0, dd, 64);
        mn = fmaxf(m0, mo); f = __expf(fminf(m0, mo) - mn);
        s0 = (m0 >= mo) ? fmaf(so, f, s0) : fmaf(s0, f, so); m0 = mn;
        mo = __shfl_xor(m1, dd, 64); so = __shfl_xor(s1, dd, 64);
        mn = fmaxf(m1, mo); f = __expf(fminf(m1, mo) - mn);
        s1 = (m1 >= mo) ? fmaf(so, f, s1) : fmaf(s1, f, so); m1 = mn;
        mo = __shfl_xor(m2, dd, 64); so = __shfl_xor(s2, dd, 64);
        mn = fmaxf(m2, mo); f = __expf(fminf(m2, mo) - mn);
        s2 = (m2 >= mo) ? fmaf(so, f, s2) : fmaf(s2, f, so); m2 = mn;
        mo = __shfl_xor(m3, dd, 64); so = __shfl_xor(s3, dd, 64);
        mn = fmaxf(m3, mo); f = __expf(fminf(m3, mo) - mn);
        s3 = (m3 >= mo) ? fmaf(so, f, s3) : fmaf(s3, f, so); m3 = mn;
    }
    float is0 = 1.f / s0, is1 = 1.f / s1, is2 = 1.f / s2, is3 = 1.f / s3;
    for (int e = rs + lane; e < re; e += 64) {
        int sn = col_idx[e];
        float4 t = *reinterpret_cast<const float4*>(&ss[sn * 4]);
        float c0 = t.x + sdn.x; c0 = (c0 > 0.f) ? c0 : 0.2f * c0;
        float c1 = t.y + sdn.y; c1 = (c1 > 0.f) ? c1 : 0.2f * c1;
        float c2 = t.z + sdn.z; c2 = (c2 > 0.f) ? c2 : 0.2f * c2;
        float c3 = t.w + sdn.w; c3 = (c3 > 0.f) ? c3 : 0.2f * c3;
        ushort4 o;
        o.x = __half_as_ushort(__float2half(__expf(c0 - m0) * is0));
        o.y = __half_as_ushort(__float2half(__expf(c1 - m1) * is1));
        o.z = __half_as_ushort(__float2half(__expf(c2 - m2) * is2));
        o.w = __half_as_ushort(__float2half(__expf(c3 - m3) * is3));
        *reinterpret_cast<ushort4*>(&alp[e * 4]) = o;
    }
}

// ---------------------------------------------------------------- weighted gather, 1 wave/node (no softmax math)
// MODE 0: concat + bias + elu -> bf16 [NN,256];  MODE 1: head-mean + bias -> f32 [NN,64]
template <int MODE>
__global__ __launch_bounds__(256) void k_agg(const ushort* __restrict__ hlin,
                                             const ushort* __restrict__ alp,
                                             const int* __restrict__ row_ptr,
                                             const int* __restrict__ col_idx,
                                             const float* __restrict__ bias,
                                             ushort* __restrict__ outb,
                                             float* __restrict__ outf) {
    int wid = threadIdx.x >> 6, lane = threadIdx.x & 63;
    int n = blockIdx.x * 4 + wid;                     // NN = 12500*4
    int h = lane >> 4, c4 = (lane & 15) << 2;
    int rs = row_ptr[n], re = row_ptr[n + 1];
    float a0 = 0.f, a1 = 0.f, a2 = 0.f, a3 = 0.f;
    int e = rs;
    for (; e + 1 < re; e += 2) {
        int sn0 = col_idx[e], sn1 = col_idx[e + 1];
        float al0 = __half2float(__ushort_as_half(alp[e * 4 + h]));
        float al1 = __half2float(__ushort_as_half(alp[(e + 1) * 4 + h]));
        ushort4 u0 = *reinterpret_cast<const ushort4*>(&hlin[sn0 * HH + (h << 6) + c4]);
        ushort4 u1 = *reinterpret_cast<const ushort4*>(&hlin[sn1 * HH + (h << 6) + c4]);
        a0 = fmaf(al0, bf2f(u0.x), a0);
        a1 = fmaf(al0, bf2f(u0.y), a1);
        a2 = fmaf(al0, bf2f(u0.z), a2);
        a3 = fmaf(al0, bf2f(u0.w), a3);
        a0 = fmaf(al1, bf2f(u1.x), a0);
        a1 = fmaf(al1, bf2f(u1.y), a1);
        a2 = fmaf(al1, bf2f(u1.z), a2);
        a3 = fmaf(al1, bf2f(u1.w), a3);
    }
    if (e < re) {
        int sn0 = col_idx[e];
        float al0 = __half2float(__ushort_as_half(alp[e * 4 + h]));
        ushort4 u0 = *reinterpret_cast<const ushort4*>(&hlin[sn0 * HH + (h << 6) + c4]);
        a0 = fmaf(al0, bf2f(u0.x), a0);
        a1 = fmaf(al0, bf2f(u0.y), a1);
        a2 = fmaf(al0, bf2f(u0.z), a2);
        a3 = fmaf(al0, bf2f(u0.w), a3);
    }
    if (MODE == 0) {
        float o0 = a0 + bias[(h << 6) + c4 + 0];
        float o1 = a1 + bias[(h << 6) + c4 + 1];
        float o2 = a2 + bias[(h << 6) + c4 + 2];
        float o3 = a3 + bias[(h << 6) + c4 + 3];
        o0 = (o0 > 0.f) ? o0 : (__expf(o0) - 1.f);    // elu
        o1 = (o1 > 0.f) ? o1 : (__expf(o1) - 1.f);
        o2 = (o2 > 0.f) ? o2 : (__expf(o2) - 1.f);
        o3 = (o3 > 0.f) ? o3 : (__expf(o3) - 1.f);
        ushort4 ob;
        ob.x = f2bf(o0); ob.y = f2bf(o1); ob.z = f2bf(o2); ob.w = f2bf(o3);
        *reinterpret_cast<ushort4*>(&outb[n * HH + (h << 6) + c4]) = ob;
    } else {
        a0 += __shfl_xor(a0, 16, 64); a0 += __shfl_xor(a0, 32, 64);
        a1 += __shfl_xor(a1, 16, 64); a1 += __shfl_xor(a1, 32, 64);
        a2 += __shfl_xor(a2, 16, 64); a2 += __shfl_xor(a2, 32, 64);
        a3 += __shfl_xor(a3, 16, 64); a3 += __shfl_xor(a3, 32, 64);
        if (h == 0) {
            float4 o = make_float4(0.25f * a0 + bias[c4 + 0],
                                   0.25f * a1 + bias[c4 + 1],
                                   0.25f * a2 + bias[c4 + 2],
                                   0.25f * a3 + bias[c4 + 3]);
            *reinterpret_cast<float4*>(&outf[n * 64 + c4]) = o;
        }
    }
}

// ---------------------------------------------------------------- mean pool, 1 block/graph (bounds fused)
__global__ __launch_bounds__(256) void k_poolG(const float* __restrict__ h,
                                               const int* __restrict__ batch,
                                               float* __restrict__ pool) {
    __shared__ float part[4][64];
    int g = blockIdx.x;
    int lo = 0, hi = NN;
    while (lo < hi) { int mid = (lo + hi) >> 1; if (batch[mid] < g) lo = mid + 1; else hi = mid; }
    int s = lo;
    lo = 0; hi = NN;
    while (lo < hi) { int mid = (lo + hi) >> 1; if (batch[mid] < g + 1) lo = mid + 1; else hi = mid; }
    int e = lo;
    int c = threadIdx.x & 63, r = threadIdx.x >> 6;
    float acc = 0.f;
    for (int n = s + r; n < e; n += 4) acc += h[n * 64 + c];
    part[r][c] = acc;
    __syncthreads();
    if (r == 0) {
        float v = part[0][c] + part[1][c] + part[2][c] + part[3][c];
        pool[g * 64 + c] = v / fmaxf((float)(e - s), 1.f);
    }
}

// ---------------------------------------------------------------- MLP head (single block), FP32 out
__global__ __launch_bounds__(256) void k_mlp(const float* __restrict__ pool,
                                             const float* __restrict__ M0W,
                                             const float* __restrict__ M0b,
                                             const float* __restrict__ M1W,
                                             const float* __restrict__ M1b,
                                             float* __restrict__ out) {
    __shared__ float g[64][64];
    __shared__ float t1[64][64];
    int tid = threadIdx.x;
    for (int idx = tid; idx < 4096; idx += 256) {
        g[idx >> 6][idx & 63] = pool[idx];       // already averaged
    }
    __syncthreads();
    for (int idx = tid; idx < 4096; idx += 256) {
        int i = idx >> 6, j = idx & 63;
        float acc = M0b[j];
        for (int k = 0; k < 64; ++k) acc = fmaf(g[i][k], M0W[k * 64 + j], acc);
        t1[i][j] = fmaxf(acc, 0.f);
    }
    __syncthreads();
    for (int idx = tid; idx < NG * DOUT; idx += 256) {
        int i = idx / DOUT, j = idx % DOUT;
        float acc = M1b[j];
        for (int k = 0; k < 64; ++k) acc = fmaf(t1[i][k], M1W[k * DOUT + j], acc);
        out[idx] = acc;                          // fp32 output (reference output dtype)
    }
}

extern "C" void kernel_launch(void* const* d_in, const int* in_sizes, int n_in,
                              void* d_out, int out_size, void* d_ws, size_t ws_size,
                              hipStream_t stream) {
    const float* x   = (const float*)d_in[0];
    const int*   ei  = (const int*)d_in[1];
    const int*   bat = (const int*)d_in[2];
    const float* A_W = (const float*)d_in[3];
    const float* A_b = (const float*)d_in[4];
    const float* W0  = (const float*)d_in[5];
    const float* as0 = (const float*)d_in[6];
    const float* ad0 = (const float*)d_in[7];
    const float* b0  = (const float*)d_in[8];
    const float* W1  = (const float*)d_in[9];
    const float* as1 = (const float*)d_in[10];
    const float* ad1 = (const float*)d_in[11];
    const float* b1  = (const float*)d_in[12];
    const float* W2  = (const float*)d_in[13];
    const float* as2 = (const float*)d_in[14];
    const float* ad2 = (const float*)d_in[15];
    const float* b2  = (const float*)d_in[16];
    const float* M0W = (const float*)d_in[17];
    const float* M0b = (const float*)d_in[18];
    const float* M1W = (const float*)d_in[19];
    const float* M1b = (const float*)d_in[20];

    char* ws = (char*)d_ws;
    ushort* hB_bf   = (ushort*)(ws);                 // 25.6 MB bf16 [NN,256] h_lin (GEMM C / gather src)
    ushort* hA_bf   = (ushort*)(ws + 25600000);      // 25.6 MB bf16 [NN,256] agg<0> out (GEMM A)
    ushort* h0_bf   = (ushort*)(ws + 51200000);      //  6.4 MB bf16 [NN,64]  input proj
    float*  h2      = (float*) (ws + 57600000);      // 12.8 MB f32  [NN,64]  agg<1> out
    float*  ss      = (float*) (ws + 70400000);      // [NN,4]
    float*  sd      = (float*) (ws + 71200000);      // [NN,4]
    int*    row_ptr = (int*)   (ws + 72000000);      // [NN+1]
    int*    cursor  = (int*)   (ws + 72200064);      // [NN] (degree, then scatter cursor)
    int*    col_idx = (int*)   (ws + 72400128);      // [NEP]
    float*  pool    = (float*) (ws + 75800128);      // [NG,64]
    ushort* Whi     = (ushort*)(ws + 75817536);      // 128 KB bf16 [256,K] col-major
    ushort* Wlo     = (ushort*)(ws + 75948608);      // 128 KB
    int*    bsum    = (int*)   (ws + 76079680);      // [256]
    int*    boff    = (int*)   (ws + 76080704);      // [256]
    ushort* alp     = (ushort*)(ws + 76081728);      //  6.8 MB fp16 [NEP,4] attention weights

    const int EB = (NEP + 255) / 256;     // 3321
    const int GB = (NN + 63) / 64;        // 782 gemm blocks

    // input projection (bf16 out)
    k_lin0b<<<(NN * 64) / 256, 256, 0, stream>>>(x, A_W, A_b, h0_bf);

    // CSR build (once per call)
    hipMemsetAsync(cursor, 0, NN * sizeof(int), stream);
    k_degree<<<EB, 256, 0, stream>>>(ei, cursor);
    k_scanA<<<256, 256, 0, stream>>>(cursor, bsum);
    k_scanB<<<1, 256, 0, stream>>>(bsum, boff, row_ptr);
    k_scanC<<<256, 256, 0, stream>>>(cursor, boff, row_ptr);   // also zeroes cursor
    k_scatter<<<EB, 256, 0, stream>>>(ei, row_ptr, cursor, col_idx);

    // layer 0 (K=64)
    k_wprep<64><<<64, 256, 0, stream>>>(W0, Whi, Wlo);
    k_gemm<64><<<GB, 256, 0, stream>>>(h0_bf, Whi, Wlo, hB_bf, as0, ad0, ss, sd);
    k_alpha<<<12500, 256, 0, stream>>>(ss, sd, row_ptr, col_idx, alp);
    k_agg<0><<<12500, 256, 0, stream>>>(hB_bf, alp, row_ptr, col_idx, b0, hA_bf, nullptr);
    // layer 1 (K=256)
    k_wprep<256><<<256, 256, 0, stream>>>(W1, Whi, Wlo);
    k_gemm<256><<<GB, 256, 0, stream>>>(hA_bf, Whi, Wlo, hB_bf, as1, ad1, ss, sd);
    k_alpha<<<12500, 256, 0, stream>>>(ss, sd, row_ptr, col_idx, alp);
    k_agg<0><<<12500, 256, 0, stream>>>(hB_bf, alp, row_ptr, col_idx, b1, hA_bf, nullptr);
    // layer 2 (K=256, head-mean -> f32 [NN,64])
    k_wprep<256><<<256, 256, 0, stream>>>(W2, Whi, Wlo);
    k_gemm<256><<<GB, 256, 0, stream>>>(hA_bf, Whi, Wlo, hB_bf, as2, ad2, ss, sd);
    k_alpha<<<12500, 256, 0, stream>>>(ss, sd, row_ptr, col_idx, alp);
    k_agg<1><<<12500, 256, 0, stream>>>(hB_bf, alp, row_ptr, col_idx, b2, nullptr, h2);

    // pooling + MLP head
    k_poolG<<<NG, 256, 0, stream>>>(h2, bat, pool);
    k_mlp<<<1, 256, 0, stream>>>(pool, M0W, M0b, M1W, M1b, (float*)d_out);
}